// Round 9
// baseline (200.264 us; speedup 1.0000x reference)
//
#include <hip/hip_runtime.h>

typedef unsigned short u16;
typedef unsigned int u32;
typedef __attribute__((ext_vector_type(8))) short short8;
typedef __attribute__((ext_vector_type(4))) float f32x4;

__device__ __forceinline__ float bl(u32 u){ return __builtin_bit_cast(float, u << 16); }
__device__ __forceinline__ float bh(u32 u){ return __builtin_bit_cast(float, u & 0xffff0000u); }
__device__ __forceinline__ float bf2f(u16 h){ return __builtin_bit_cast(float, ((u32)h) << 16); }
__device__ __forceinline__ u16 f2bf(float f){
  u32 u = __builtin_bit_cast(u32, f);
  u32 r = u + 0x7fffu + ((u >> 16) & 1u);
  return (u16)(r >> 16);
}

// ------- Kernel 0 (fused prep, one launch):
//   blocks [0,1024):    x fp32 [b][c][hw] -> XTh/XTl bf16 hi/lo, pixel-major [pix][c]
//   blocks [1024,1088): w3 -> W3h bf16 (hi only)
//   blocks [1088,1344): M = W1^T W2 fp32 -> Mh/Ml bf16 hi/lo
__global__ __launch_bounds__(256) void prep(const float* __restrict__ x,
                                            const float* __restrict__ w1,
                                            const float* __restrict__ w2,
                                            const float* __restrict__ w3,
                                            u16* __restrict__ XTh,
                                            u16* __restrict__ XTl,
                                            u16* __restrict__ W3h,
                                            u16* __restrict__ Mh,
                                            u16* __restrict__ Ml)
{
  __shared__ float tile[64 * 68];
  const int bi = blockIdx.x;
  const int t = threadIdx.x;

  if (bi < 1024) {
    int hw0 = (bi & 63) * 64, c0 = ((bi >> 6) & 3) * 64, b = bi >> 8;
    {
      int cl = t >> 2, seg = (t & 3) * 16;
      const float* src = x + (b * 256 + c0 + cl) * 4096 + hw0 + seg;
      float4 v0 = ((const float4*)src)[0];
      float4 v1 = ((const float4*)src)[1];
      float4 v2 = ((const float4*)src)[2];
      float4 v3 = ((const float4*)src)[3];
      float* d = tile + cl * 68 + seg;
      ((float4*)d)[0] = v0; ((float4*)d)[1] = v1;
      ((float4*)d)[2] = v2; ((float4*)d)[3] = v3;
    }
    __syncthreads();
    {
      int hwl = t >> 2, cs = (t & 3) * 16;
      u32 ph[8], pl[8];
      #pragma unroll
      for (int e = 0; e < 8; ++e) {
        float v0 = tile[(cs + 2 * e) * 68 + hwl];
        float v1 = tile[(cs + 2 * e + 1) * 68 + hwl];
        u16 h0 = f2bf(v0), h1 = f2bf(v1);
        u16 l0 = f2bf(v0 - bf2f(h0)), l1 = f2bf(v1 - bf2f(h1));
        ph[e] = (u32)h0 | ((u32)h1 << 16);
        pl[e] = (u32)l0 | ((u32)l1 << 16);
      }
      int off = (b * 4096 + hw0 + hwl) * 256 + c0 + cs;
      *(uint4*)(XTh + off)     = make_uint4(ph[0], ph[1], ph[2], ph[3]);
      *(uint4*)(XTh + off + 8) = make_uint4(ph[4], ph[5], ph[6], ph[7]);
      *(uint4*)(XTl + off)     = make_uint4(pl[0], pl[1], pl[2], pl[3]);
      *(uint4*)(XTl + off + 8) = make_uint4(pl[4], pl[5], pl[6], pl[7]);
    }
  } else if (bi < 1088) {
    int i = ((bi - 1024) * 256 + t) * 4;
    float4 v = *(const float4*)(w3 + i);
    u16 h0 = f2bf(v.x), h1 = f2bf(v.y), h2 = f2bf(v.z), h3 = f2bf(v.w);
    uint2 hv; hv.x = (u32)h0 | ((u32)h1 << 16); hv.y = (u32)h2 | ((u32)h3 << 16);
    *(uint2*)(W3h + i) = hv;
  } else {
    const int i = bi - 1088, j = t;
    float acc = 0.f;
    #pragma unroll 16
    for (int o = 0; o < 256; ++o)
      acc = fmaf(w1[o * 256 + i], w2[o * 256 + j], acc);
    u16 hh = f2bf(acc);
    u16 ll = f2bf(acc - bf2f(hh));
    Mh[i * 256 + j] = hh;
    Ml[i * 256 + j] = ll;
  }
}

// ------- Kernel 1: z=0 -> y = M x (3-pass split-bf16) -> yh/yl pixel-major;
//         z=1 -> v = W3 x (1-pass) -> vo c-major. grid (128, 2, 2). -------
#define LSTR 40
__global__ __launch_bounds__(256) void yv_gemm(const u16* __restrict__ XTh,
                                               const u16* __restrict__ XTl,
                                               const u16* __restrict__ Mh,
                                               const u16* __restrict__ Ml,
                                               const u16* __restrict__ W3h,
                                               u16* __restrict__ yh_, u16* __restrict__ yl_,
                                               u16* __restrict__ vo)
{
  __shared__ u16 lAh[128 * LSTR];
  __shared__ u16 lBh[128 * LSTR];
  __shared__ u16 lAl[128 * LSTR];
  __shared__ u16 lBl[128 * LSTR];
  int z = blockIdx.z;
  int t = threadIdx.x;
  int lane = t & 63, wv = t >> 6;
  int ln15 = lane & 15, q = lane >> 4;
  int pix0 = blockIdx.x * 128;
  int o0 = blockIdx.y * 128;
  int pw = (wv >> 1) * 64, ow = (wv & 1) * 64;
  f32x4 acc[4][4];
  #pragma unroll
  for (int i = 0; i < 4; ++i)
    #pragma unroll
    for (int j = 0; j < 4; ++j)
      acc[i][j] = (f32x4){0.f, 0.f, 0.f, 0.f};

  int srow = t >> 1;
  int sseg = (t & 1) * 16;
  const u16* gAh = XTh + (pix0 + srow) * 256 + sseg;
  const u16* gAl = XTl + (pix0 + srow) * 256 + sseg;
  const u16* gBh = ((z == 0) ? Mh : W3h) + (o0 + srow) * 256 + sseg;
  const u16* gBl = Ml + (o0 + srow) * 256 + sseg;
  u16* sAh = lAh + srow * LSTR + sseg;
  u16* sAl = lAl + srow * LSTR + sseg;
  u16* sBh = lBh + srow * LSTR + sseg;
  u16* sBl = lBl + srow * LSTR + sseg;

  for (int kc = 0; kc < 256; kc += 32) {
    uint4 ah0 = *(const uint4*)(gAh + kc);
    uint4 ah1 = *(const uint4*)(gAh + kc + 8);
    uint4 bh0 = *(const uint4*)(gBh + kc);
    uint4 bh1 = *(const uint4*)(gBh + kc + 8);
    uint4 al0 = make_uint4(0,0,0,0), al1 = make_uint4(0,0,0,0);
    uint4 bl0 = make_uint4(0,0,0,0), bl1 = make_uint4(0,0,0,0);
    if (z == 0) {
      al0 = *(const uint4*)(gAl + kc);
      al1 = *(const uint4*)(gAl + kc + 8);
      bl0 = *(const uint4*)(gBl + kc);
      bl1 = *(const uint4*)(gBl + kc + 8);
    }
    __syncthreads();
    *(uint4*)sAh = ah0; *(uint4*)(sAh + 8) = ah1;
    *(uint4*)sBh = bh0; *(uint4*)(sBh + 8) = bh1;
    if (z == 0) {
      *(uint4*)sAl = al0; *(uint4*)(sAl + 8) = al1;
      *(uint4*)sBl = bl0; *(uint4*)(sBl + 8) = bl1;
    }
    __syncthreads();
    short8 afh[4], bfh[4];
    #pragma unroll
    for (int i = 0; i < 4; ++i)
      afh[i] = *(const short8*)(lAh + (pw + i * 16 + ln15) * LSTR + q * 8);
    #pragma unroll
    for (int j = 0; j < 4; ++j)
      bfh[j] = *(const short8*)(lBh + (ow + j * 16 + ln15) * LSTR + q * 8);
    #pragma unroll
    for (int i = 0; i < 4; ++i)
      #pragma unroll
      for (int j = 0; j < 4; ++j)
        acc[i][j] = __builtin_amdgcn_mfma_f32_16x16x32_bf16(afh[i], bfh[j], acc[i][j], 0, 0, 0);
    if (z == 0) {
      short8 afl[4], bfl[4];
      #pragma unroll
      for (int i = 0; i < 4; ++i)
        afl[i] = *(const short8*)(lAl + (pw + i * 16 + ln15) * LSTR + q * 8);
      #pragma unroll
      for (int j = 0; j < 4; ++j)
        bfl[j] = *(const short8*)(lBl + (ow + j * 16 + ln15) * LSTR + q * 8);
      #pragma unroll
      for (int i = 0; i < 4; ++i)
        #pragma unroll
        for (int j = 0; j < 4; ++j) {
          acc[i][j] = __builtin_amdgcn_mfma_f32_16x16x32_bf16(afh[i], bfl[j], acc[i][j], 0, 0, 0);
          acc[i][j] = __builtin_amdgcn_mfma_f32_16x16x32_bf16(afl[i], bfh[j], acc[i][j], 0, 0, 0);
        }
    }
  }

  __syncthreads();   // all frag reads of lA*/lB* done; safe to repurpose as staging

  // D: m(pixel) = pw + i*16 + q*4 + r, n(o) = ow + j*16 + ln15
  if (z == 1) {
    #pragma unroll
    for (int i = 0; i < 4; ++i) {
      int pixb = pix0 + pw + i * 16 + q * 4;
      #pragma unroll
      for (int j = 0; j < 4; ++j) {
        int o = o0 + ow + j * 16 + ln15;
        u32 p0 = (u32)f2bf(acc[i][j][0]) | ((u32)f2bf(acc[i][j][1]) << 16);
        u32 p1 = (u32)f2bf(acc[i][j][2]) | ((u32)f2bf(acc[i][j][3]) << 16);
        uint2 pv; pv.x = p0; pv.y = p1;
        *(uint2*)(vo + o * 16384 + pixb) = pv;
      }
    }
  } else {
    // y epilogue: per-wave LDS transpose (16 pix x 64 ob, stride 72) -> coalesced uint4 stores
    u16* sth = lAh + wv * 1152;
    u16* stl = lAl + wv * 1152;
    const int pixl = lane >> 2, seg = lane & 3;
    #pragma unroll
    for (int i = 0; i < 4; ++i) {
      #pragma unroll
      for (int j = 0; j < 4; ++j)
        #pragma unroll
        for (int r = 0; r < 4; ++r) {
          float vv = acc[i][j][r];
          u16 hh = f2bf(vv);
          u16 ll = f2bf(vv - bf2f(hh));
          sth[(q * 4 + r) * 72 + j * 16 + ln15] = hh;
          stl[(q * 4 + r) * 72 + j * 16 + ln15] = ll;
        }
      // wave-private region; compiler inserts lgkmcnt waits for write->read ordering
      const u16* srch = sth + pixl * 72 + seg * 16;
      const u16* srcl = stl + pixl * 72 + seg * 16;
      uint4 h0 = *(const uint4*)srch;
      uint4 h1 = *(const uint4*)(srch + 8);
      uint4 l0 = *(const uint4*)srcl;
      uint4 l1 = *(const uint4*)(srcl + 8);
      int pix = pix0 + pw + i * 16 + pixl;
      int ob = o0 + ow + seg * 16;
      *(uint4*)(yh_ + pix * 256 + ob)     = h0;
      *(uint4*)(yh_ + pix * 256 + ob + 8) = h1;
      *(uint4*)(yl_ + pix * 256 + ob)     = l0;
      *(uint4*)(yl_ + pix * 256 + ob + 8) = l1;
    }
  }
}

// ------- Kernel 2: banded-MFMA local attention. Block = quarter-row (16 px), 4 waves.
// grid 1024, XCD-banded swizzle. Branch-free dh loops (clamped row + predicated loads). -------
__global__ __launch_bounds__(256, 4) void attn(const u16* __restrict__ xh_,
                                               const u16* __restrict__ xl_,
                                               const u16* __restrict__ yh_,
                                               const u16* __restrict__ yl_,
                                               const u16* __restrict__ vo,
                                               float* __restrict__ out)
{
  __shared__ float lg2[4][16][57];       // logits by c-quarter (summed in softmax)
  __shared__ u16 pb[7][16][40];          // banded prob B-operand [dh][m'][slot(pad 40)]

  const int t = threadIdx.x;
  const int lane = t & 63, wv = t >> 6;
  const int l15 = lane & 15, q4 = lane >> 4;
  // XCD swizzle: blocks round-robin over 8 XCDs; XCD (bi&7) gets a contiguous
  // 32-row band (128 units) so co-resident blocks share y/v rows in its L2.
  const int bi = blockIdx.x;
  const int unit = ((bi & 7) << 7) | (bi >> 3);
  const int quar = unit & 3;
  const int row = unit >> 2;              // b*64 + h
  const int b = row >> 6, h = row & 63;
  const int wbase = quar * 16;

  for (int i = t; i < 4 * 16 * 57; i += 256) ((float*)lg2)[i] = 0.f;
  for (int i = t; i < 2240; i += 256) ((u32*)pb)[i] = 0u;
  __syncthreads();

  const short8 zf = {0, 0, 0, 0, 0, 0, 0, 0};

  // ---------- phase 1: logits (wave = c-quarter ch=wv) ----------
  {
    const int ch = wv;
    short8 qfh[2], qfl[2];
    {
      const int pix = row * 64 + wbase + l15;  // A: m = l15 (query pixel)
      const u16* qhp = xh_ + pix * 256;
      const u16* qlp = xl_ + pix * 256;
      #pragma unroll
      for (int u = 0; u < 2; ++u) {
        const int c0 = ch * 64 + u * 32 + q4 * 8;
        qfh[u] = *(const short8*)(qhp + c0);
        qfl[u] = *(const short8*)(qlp + c0);
      }
    }
    const int wn0 = wbase - 8 + l15;           // win0 neighbor w (B: n = l15)
    const int wn1 = wbase + 8 + l15;           // win1 neighbor w
    const bool ok0 = (wn0 >= 0) && (wn0 < 64);
    const bool ok1 = (wn1 >= 0) && (wn1 < 64);
    for (int dh = 0; dh < 7; ++dh) {
      int krow = h + dh - 3;
      const bool rowok = (krow >= 0) && (krow < 64);
      krow = krow < 0 ? 0 : (krow > 63 ? 63 : krow);
      const int rp = (row - h + krow) * 64;    // clamped, always in-image
      const bool k0 = ok0 && rowok, k1 = ok1 && rowok;
      const u16* k0hp = yh_ + (rp + wn0) * 256;
      const u16* k0lp = yl_ + (rp + wn0) * 256;
      const u16* k1hp = yh_ + (rp + wn1) * 256;
      const u16* k1lp = yl_ + (rp + wn1) * 256;
      f32x4 a0 = {0.f, 0.f, 0.f, 0.f}, a1 = {0.f, 0.f, 0.f, 0.f};
      #pragma unroll
      for (int u = 0; u < 2; ++u) {
        const int c0 = ch * 64 + u * 32 + q4 * 8;
        short8 b0h = k0 ? *(const short8*)(k0hp + c0) : zf;
        short8 b1h = k1 ? *(const short8*)(k1hp + c0) : zf;
        short8 b0l = k0 ? *(const short8*)(k0lp + c0) : zf;
        short8 b1l = k1 ? *(const short8*)(k1lp + c0) : zf;
        a0 = __builtin_amdgcn_mfma_f32_16x16x32_bf16(qfh[u], b0h, a0, 0, 0, 0);
        a1 = __builtin_amdgcn_mfma_f32_16x16x32_bf16(qfh[u], b1h, a1, 0, 0, 0);
        a0 = __builtin_amdgcn_mfma_f32_16x16x32_bf16(qfh[u], b0l, a0, 0, 0, 0);
        a1 = __builtin_amdgcn_mfma_f32_16x16x32_bf16(qfh[u], b1l, a1, 0, 0, 0);
        a0 = __builtin_amdgcn_mfma_f32_16x16x32_bf16(qfl[u], b0h, a0, 0, 0, 0);
        a1 = __builtin_amdgcn_mfma_f32_16x16x32_bf16(qfl[u], b1h, a1, 0, 0, 0);
      }
      // scatter band entries: D col n=l15, row m=q4*4+r; dw = n_w - m_w - 5 (+16 win1)
      #pragma unroll
      for (int r = 0; r < 4; ++r) {
        const int mloc = q4 * 4 + r;
        const int dw0 = l15 - mloc - 5;
        const int dw1 = dw0 + 16;
        if (dw0 >= 0 && dw0 < 7) lg2[ch][mloc][dh * 7 + dw0] = a0[r];
        if (dw1 >= 0 && dw1 < 7) lg2[ch][mloc][dh * 7 + dw1] = a1[r];
      }
    }
  }
  __syncthreads();

  // ---------- softmax (t < 16: one thread per pixel) ----------
  if (t < 16) {
    float mx = -3.0e38f;
    for (int i = 0; i < 49; ++i)
      mx = fmaxf(mx, lg2[0][t][i] + lg2[1][t][i] + lg2[2][t][i] + lg2[3][t][i]);
    float s = 0.f;
    for (int i = 0; i < 49; ++i)
      s += __expf(lg2[0][t][i] + lg2[1][t][i] + lg2[2][t][i] + lg2[3][t][i] - mx);
    const float inv = 1.f / s;
    #pragma unroll
    for (int dh = 0; dh < 7; ++dh)
      #pragma unroll
      for (int dw = 0; dw < 7; ++dw) {
        float l = lg2[0][t][dh * 7 + dw] + lg2[1][t][dh * 7 + dw]
                + lg2[2][t][dh * 7 + dw] + lg2[3][t][dh * 7 + dw];
        pb[dh][t][t + 5 + dw] = f2bf(__expf(l - mx) * inv);
      }
  }
  __syncthreads();

  // ---------- phase 2: out[c][m'] = sum_slot v[c][slot] * P[m'][slot] ----------
  const int wo = wbase - 8 + q4 * 8;       // A k-octet start (w coord)
  const bool wok = (wo >= 0) && (wo <= 56);
  #pragma unroll
  for (int i = 0; i < 4; ++i) {
    const int ct = wv * 4 + i;               // c-tile (16 channels)
    const u16* vbase = vo + (ct * 16 + l15) * 16384 + wo;  // A: m = l15 (channel)
    f32x4 acc = {0.f, 0.f, 0.f, 0.f};
    for (int dh = 0; dh < 7; ++dh) {
      int krow = h + dh - 3;
      const bool rowok = (krow >= 0) && (krow < 64);
      krow = krow < 0 ? 0 : (krow > 63 ? 63 : krow);
      const int rp = (row - h + krow) * 64;
      const bool vk = wok && rowok;
      short8 af = vk ? *(const short8*)(vbase + rp) : zf;
      short8 bf_ = *(const short8*)(&pb[dh][l15][q4 * 8]);
      acc = __builtin_amdgcn_mfma_f32_16x16x32_bf16(af, bf_, acc, 0, 0, 0);
    }
    // D: row m = channel q4*4+r, col n = pixel l15 -> native [b][c][h][w]
    #pragma unroll
    for (int r = 0; r < 4; ++r)
      out[(b * 256 + ct * 16 + q4 * 4 + r) * 4096 + h * 64 + wbase + l15] = acc[r];
  }
}

extern "C" void kernel_launch(void* const* d_in, const int* in_sizes, int n_in,
                              void* d_out, int out_size, void* d_ws, size_t ws_size,
                              hipStream_t stream)
{
  const float* x  = (const float*)d_in[0];
  const float* w1 = (const float*)d_in[1];
  const float* w2 = (const float*)d_in[2];
  const float* w3 = (const float*)d_in[3];
  float* out = (float*)d_out;

  char* ws = (char*)d_ws;
  u16* XTh = (u16*)ws;                     // 8 MB bf16 hi(x), pixel-major [pix][c]
  u16* XTl = (u16*)(ws + (8u  << 20));     // 8 MB bf16 lo(x)
  u16* yh_ = (u16*)(ws + (16u << 20));     // 8 MB bf16 hi(y = Mx), pixel-major
  u16* yl_ = (u16*)(ws + (24u << 20));     // 8 MB bf16 lo(y)
  u16* vo  = (u16*)(ws + (32u << 20));     // 8 MB bf16 v, c-major [c][pix]
  u16* W3h = (u16*)(ws + (40u << 20));     // 128 KB
  u16* Mh  = W3h + 65536;                  // 128 KB
  u16* Ml  = Mh + 65536;                   // 128 KB

  prep<<<1344, 256, 0, stream>>>(x, w1, w2, w3, XTh, XTl, W3h, Mh, Ml);
  yv_gemm<<<dim3(128, 2, 2), 256, 0, stream>>>(XTh, XTl, Mh, Ml, W3h, yh_, yl_, vo);
  attn<<<1024, 256, 0, stream>>>(XTh, XTl, yh_, yl_, vo, out);
}

// Round 10
// 154.913 us; speedup vs baseline: 1.2928x; 1.2928x over previous
//
#include <hip/hip_runtime.h>

typedef unsigned short u16;
typedef unsigned int u32;
typedef __attribute__((ext_vector_type(8))) short short8;
typedef __attribute__((ext_vector_type(4))) float f32x4;

__device__ __forceinline__ float bl(u32 u){ return __builtin_bit_cast(float, u << 16); }
__device__ __forceinline__ float bh(u32 u){ return __builtin_bit_cast(float, u & 0xffff0000u); }
__device__ __forceinline__ float bf2f(u16 h){ return __builtin_bit_cast(float, ((u32)h) << 16); }
__device__ __forceinline__ u16 f2bf(float f){
  u32 u = __builtin_bit_cast(u32, f);
  u32 r = u + 0x7fffu + ((u >> 16) & 1u);
  return (u16)(r >> 16);
}

// ------- Kernel 0 (fused prep, one launch):
//   blocks [0,1024):    x fp32 [b][c][hw] -> XTh/XTl bf16 hi/lo, pixel-major [pix][c]
//   blocks [1024,1088): w3 -> W3h bf16 (hi only)
//   blocks [1088,1344): M = W1^T W2 fp32 -> Mh/Ml bf16 hi/lo
__global__ __launch_bounds__(256) void prep(const float* __restrict__ x,
                                            const float* __restrict__ w1,
                                            const float* __restrict__ w2,
                                            const float* __restrict__ w3,
                                            u16* __restrict__ XTh,
                                            u16* __restrict__ XTl,
                                            u16* __restrict__ W3h,
                                            u16* __restrict__ Mh,
                                            u16* __restrict__ Ml)
{
  __shared__ float tile[64 * 68];
  const int bi = blockIdx.x;
  const int t = threadIdx.x;

  if (bi < 1024) {
    int hw0 = (bi & 63) * 64, c0 = ((bi >> 6) & 3) * 64, b = bi >> 8;
    {
      int cl = t >> 2, seg = (t & 3) * 16;
      const float* src = x + (b * 256 + c0 + cl) * 4096 + hw0 + seg;
      float4 v0 = ((const float4*)src)[0];
      float4 v1 = ((const float4*)src)[1];
      float4 v2 = ((const float4*)src)[2];
      float4 v3 = ((const float4*)src)[3];
      float* d = tile + cl * 68 + seg;
      ((float4*)d)[0] = v0; ((float4*)d)[1] = v1;
      ((float4*)d)[2] = v2; ((float4*)d)[3] = v3;
    }
    __syncthreads();
    {
      int hwl = t >> 2, cs = (t & 3) * 16;
      u32 ph[8], pl[8];
      #pragma unroll
      for (int e = 0; e < 8; ++e) {
        float v0 = tile[(cs + 2 * e) * 68 + hwl];
        float v1 = tile[(cs + 2 * e + 1) * 68 + hwl];
        u16 h0 = f2bf(v0), h1 = f2bf(v1);
        u16 l0 = f2bf(v0 - bf2f(h0)), l1 = f2bf(v1 - bf2f(h1));
        ph[e] = (u32)h0 | ((u32)h1 << 16);
        pl[e] = (u32)l0 | ((u32)l1 << 16);
      }
      int off = (b * 4096 + hw0 + hwl) * 256 + c0 + cs;
      *(uint4*)(XTh + off)     = make_uint4(ph[0], ph[1], ph[2], ph[3]);
      *(uint4*)(XTh + off + 8) = make_uint4(ph[4], ph[5], ph[6], ph[7]);
      *(uint4*)(XTl + off)     = make_uint4(pl[0], pl[1], pl[2], pl[3]);
      *(uint4*)(XTl + off + 8) = make_uint4(pl[4], pl[5], pl[6], pl[7]);
    }
  } else if (bi < 1088) {
    int i = ((bi - 1024) * 256 + t) * 4;
    float4 v = *(const float4*)(w3 + i);
    u16 h0 = f2bf(v.x), h1 = f2bf(v.y), h2 = f2bf(v.z), h3 = f2bf(v.w);
    uint2 hv; hv.x = (u32)h0 | ((u32)h1 << 16); hv.y = (u32)h2 | ((u32)h3 << 16);
    *(uint2*)(W3h + i) = hv;
  } else {
    const int i = bi - 1088, j = t;
    float acc = 0.f;
    #pragma unroll 16
    for (int o = 0; o < 256; ++o)
      acc = fmaf(w1[o * 256 + i], w2[o * 256 + j], acc);
    u16 hh = f2bf(acc);
    u16 ll = f2bf(acc - bf2f(hh));
    Mh[i * 256 + j] = hh;
    Ml[i * 256 + j] = ll;
  }
}

// ------- Kernel 1: z=0 -> y = M x (3-pass split-bf16) -> yh/yl pixel-major;
//         z=1 -> v = W3 x (1-pass) -> vo c-major. grid (128, 2, 2). -------
#define LSTR 40
__global__ __launch_bounds__(256) void yv_gemm(const u16* __restrict__ XTh,
                                               const u16* __restrict__ XTl,
                                               const u16* __restrict__ Mh,
                                               const u16* __restrict__ Ml,
                                               const u16* __restrict__ W3h,
                                               u16* __restrict__ yh_, u16* __restrict__ yl_,
                                               u16* __restrict__ vo)
{
  __shared__ u16 lAh[128 * LSTR];
  __shared__ u16 lBh[128 * LSTR];
  __shared__ u16 lAl[128 * LSTR];
  __shared__ u16 lBl[128 * LSTR];
  int z = blockIdx.z;
  int t = threadIdx.x;
  int lane = t & 63, wv = t >> 6;
  int ln15 = lane & 15, q = lane >> 4;
  int pix0 = blockIdx.x * 128;
  int o0 = blockIdx.y * 128;
  int pw = (wv >> 1) * 64, ow = (wv & 1) * 64;
  f32x4 acc[4][4];
  #pragma unroll
  for (int i = 0; i < 4; ++i)
    #pragma unroll
    for (int j = 0; j < 4; ++j)
      acc[i][j] = (f32x4){0.f, 0.f, 0.f, 0.f};

  int srow = t >> 1;
  int sseg = (t & 1) * 16;
  const u16* gAh = XTh + (pix0 + srow) * 256 + sseg;
  const u16* gAl = XTl + (pix0 + srow) * 256 + sseg;
  const u16* gBh = ((z == 0) ? Mh : W3h) + (o0 + srow) * 256 + sseg;
  const u16* gBl = Ml + (o0 + srow) * 256 + sseg;
  u16* sAh = lAh + srow * LSTR + sseg;
  u16* sAl = lAl + srow * LSTR + sseg;
  u16* sBh = lBh + srow * LSTR + sseg;
  u16* sBl = lBl + srow * LSTR + sseg;

  for (int kc = 0; kc < 256; kc += 32) {
    uint4 ah0 = *(const uint4*)(gAh + kc);
    uint4 ah1 = *(const uint4*)(gAh + kc + 8);
    uint4 bh0 = *(const uint4*)(gBh + kc);
    uint4 bh1 = *(const uint4*)(gBh + kc + 8);
    uint4 al0 = make_uint4(0,0,0,0), al1 = make_uint4(0,0,0,0);
    uint4 bl0 = make_uint4(0,0,0,0), bl1 = make_uint4(0,0,0,0);
    if (z == 0) {
      al0 = *(const uint4*)(gAl + kc);
      al1 = *(const uint4*)(gAl + kc + 8);
      bl0 = *(const uint4*)(gBl + kc);
      bl1 = *(const uint4*)(gBl + kc + 8);
    }
    __syncthreads();
    *(uint4*)sAh = ah0; *(uint4*)(sAh + 8) = ah1;
    *(uint4*)sBh = bh0; *(uint4*)(sBh + 8) = bh1;
    if (z == 0) {
      *(uint4*)sAl = al0; *(uint4*)(sAl + 8) = al1;
      *(uint4*)sBl = bl0; *(uint4*)(sBl + 8) = bl1;
    }
    __syncthreads();
    short8 afh[4], bfh[4];
    #pragma unroll
    for (int i = 0; i < 4; ++i)
      afh[i] = *(const short8*)(lAh + (pw + i * 16 + ln15) * LSTR + q * 8);
    #pragma unroll
    for (int j = 0; j < 4; ++j)
      bfh[j] = *(const short8*)(lBh + (ow + j * 16 + ln15) * LSTR + q * 8);
    #pragma unroll
    for (int i = 0; i < 4; ++i)
      #pragma unroll
      for (int j = 0; j < 4; ++j)
        acc[i][j] = __builtin_amdgcn_mfma_f32_16x16x32_bf16(afh[i], bfh[j], acc[i][j], 0, 0, 0);
    if (z == 0) {
      short8 afl[4], bfl[4];
      #pragma unroll
      for (int i = 0; i < 4; ++i)
        afl[i] = *(const short8*)(lAl + (pw + i * 16 + ln15) * LSTR + q * 8);
      #pragma unroll
      for (int j = 0; j < 4; ++j)
        bfl[j] = *(const short8*)(lBl + (ow + j * 16 + ln15) * LSTR + q * 8);
      #pragma unroll
      for (int i = 0; i < 4; ++i)
        #pragma unroll
        for (int j = 0; j < 4; ++j) {
          acc[i][j] = __builtin_amdgcn_mfma_f32_16x16x32_bf16(afh[i], bfl[j], acc[i][j], 0, 0, 0);
          acc[i][j] = __builtin_amdgcn_mfma_f32_16x16x32_bf16(afl[i], bfh[j], acc[i][j], 0, 0, 0);
        }
    }
  }

  __syncthreads();   // all frag reads of lA*/lB* done; safe to repurpose as staging

  // D: m(pixel) = pw + i*16 + q*4 + r, n(o) = ow + j*16 + ln15
  if (z == 1) {
    #pragma unroll
    for (int i = 0; i < 4; ++i) {
      int pixb = pix0 + pw + i * 16 + q * 4;
      #pragma unroll
      for (int j = 0; j < 4; ++j) {
        int o = o0 + ow + j * 16 + ln15;
        u32 p0 = (u32)f2bf(acc[i][j][0]) | ((u32)f2bf(acc[i][j][1]) << 16);
        u32 p1 = (u32)f2bf(acc[i][j][2]) | ((u32)f2bf(acc[i][j][3]) << 16);
        uint2 pv; pv.x = p0; pv.y = p1;
        *(uint2*)(vo + o * 16384 + pixb) = pv;
      }
    }
  } else {
    // y epilogue: per-wave LDS transpose (16 pix x 64 ob, stride 72) -> coalesced uint4 stores
    u16* sth = lAh + wv * 1152;
    u16* stl = lAl + wv * 1152;
    const int pixl = lane >> 2, seg = lane & 3;
    #pragma unroll
    for (int i = 0; i < 4; ++i) {
      #pragma unroll
      for (int j = 0; j < 4; ++j)
        #pragma unroll
        for (int r = 0; r < 4; ++r) {
          float vv = acc[i][j][r];
          u16 hh = f2bf(vv);
          u16 ll = f2bf(vv - bf2f(hh));
          sth[(q * 4 + r) * 72 + j * 16 + ln15] = hh;
          stl[(q * 4 + r) * 72 + j * 16 + ln15] = ll;
        }
      const u16* srch = sth + pixl * 72 + seg * 16;
      const u16* srcl = stl + pixl * 72 + seg * 16;
      uint4 h0 = *(const uint4*)srch;
      uint4 h1 = *(const uint4*)(srch + 8);
      uint4 l0 = *(const uint4*)srcl;
      uint4 l1 = *(const uint4*)(srcl + 8);
      int pix = pix0 + pw + i * 16 + pixl;
      int ob = o0 + ow + seg * 16;
      *(uint4*)(yh_ + pix * 256 + ob)     = h0;
      *(uint4*)(yh_ + pix * 256 + ob + 8) = h1;
      *(uint4*)(yl_ + pix * 256 + ob)     = l0;
      *(uint4*)(yl_ + pix * 256 + ob + 8) = l1;
    }
  }
}

// ------- Kernel 2: banded-MFMA local attention (r8-proven). Block = half row (32 px),
// 4 waves, grid 512, XCD-banded swizzle. -------
__global__ __launch_bounds__(256, 2) void attn(const u16* __restrict__ xh_,
                                               const u16* __restrict__ xl_,
                                               const u16* __restrict__ yh_,
                                               const u16* __restrict__ yl_,
                                               const u16* __restrict__ vo,
                                               float* __restrict__ out)
{
  __shared__ float lg2[2][32][57];       // logits, split by c-half (summed in softmax)
  __shared__ u16 pb[2][7][16][40];       // banded prob B-operand [mt][dh][m'][n'(pad 40)]

  const int t = threadIdx.x;
  const int lane = t & 63, wv = t >> 6;
  const int l15 = lane & 15, q4 = lane >> 4;
  // XCD-aware swizzle: dispatch round-robins blocks over 8 XCDs; give XCD (i&7)
  // a contiguous 32-row band so its 64 co-resident blocks share y/v rows in L2.
  const int bi = blockIdx.x;
  const int unit = ((bi & 7) << 6) | (bi >> 3);
  const int half = unit & 1;
  const int row = unit >> 1;              // b*64 + h
  const int b = row >> 6, h = row & 63;

  for (int i = t; i < 2 * 32 * 57; i += 256) ((float*)lg2)[i] = 0.f;
  for (int i = t; i < 4480; i += 256) ((u32*)pb)[i] = 0u;
  __syncthreads();

  const short8 zf = {0, 0, 0, 0, 0, 0, 0, 0};

  // ---------- phase 1: logits ----------
  {
    const int mt = wv >> 1, ch = wv & 1;       // wave -> (m-tile, c-half)
    const int wbase = half * 32 + mt * 16;     // m-tile w start
    short8 qfh[4], qfl[4];
    {
      const int pix = row * 64 + wbase + l15;  // A: m = l15 (query pixel), query = x
      const u16* qhp = xh_ + pix * 256;
      const u16* qlp = xl_ + pix * 256;
      #pragma unroll
      for (int u = 0; u < 4; ++u) {
        const int c0 = (ch * 4 + u) * 32 + q4 * 8;
        qfh[u] = *(const short8*)(qhp + c0);
        qfl[u] = *(const short8*)(qlp + c0);
      }
    }
    const int wn0 = wbase - 8 + l15;           // win0 neighbor w (B: n = l15)
    const int wn1 = wbase + 8 + l15;           // win1 neighbor w
    const bool ok0 = (wn0 >= 0) && (wn0 < 64);
    const bool ok1 = (wn1 >= 0) && (wn1 < 64);
    for (int dh = 0; dh < 7; ++dh) {
      const int rdh = h + dh - 3;
      if (rdh < 0 || rdh >= 64) continue;      // OOB row: logits stay 0 (pre-zeroed)
      const int rp = (row + dh - 3) * 64;
      const u16* k0h = yh_ + (rp + wn0) * 256;
      const u16* k0l = yl_ + (rp + wn0) * 256;
      const u16* k1h = yh_ + (rp + wn1) * 256;
      const u16* k1l = yl_ + (rp + wn1) * 256;
      f32x4 a0 = {0.f, 0.f, 0.f, 0.f}, a1 = {0.f, 0.f, 0.f, 0.f};
      #pragma unroll
      for (int u = 0; u < 4; ++u) {
        const int c0 = (ch * 4 + u) * 32 + q4 * 8;
        short8 b0h = ok0 ? *(const short8*)(k0h + c0) : zf;
        short8 b1h = ok1 ? *(const short8*)(k1h + c0) : zf;
        short8 b0l = ok0 ? *(const short8*)(k0l + c0) : zf;
        short8 b1l = ok1 ? *(const short8*)(k1l + c0) : zf;
        a0 = __builtin_amdgcn_mfma_f32_16x16x32_bf16(qfh[u], b0h, a0, 0, 0, 0);
        a1 = __builtin_amdgcn_mfma_f32_16x16x32_bf16(qfh[u], b1h, a1, 0, 0, 0);
        a0 = __builtin_amdgcn_mfma_f32_16x16x32_bf16(qfh[u], b0l, a0, 0, 0, 0);
        a1 = __builtin_amdgcn_mfma_f32_16x16x32_bf16(qfh[u], b1l, a1, 0, 0, 0);
        a0 = __builtin_amdgcn_mfma_f32_16x16x32_bf16(qfl[u], b0h, a0, 0, 0, 0);
        a1 = __builtin_amdgcn_mfma_f32_16x16x32_bf16(qfl[u], b1h, a1, 0, 0, 0);
      }
      // scatter band entries: D col n=l15, row m=q4*4+r; dw = n_w - m_w + 3
      #pragma unroll
      for (int r = 0; r < 4; ++r) {
        const int mloc = mt * 16 + q4 * 4 + r;
        const int dw0 = l15 - q4 * 4 - r - 5;
        const int dw1 = dw0 + 16;
        if (dw0 >= 0 && dw0 < 7) lg2[ch][mloc][dh * 7 + dw0] = a0[r];
        if (dw1 >= 0 && dw1 < 7) lg2[ch][mloc][dh * 7 + dw1] = a1[r];
      }
    }
  }
  __syncthreads();

  // ---------- softmax (t < 32: one thread per pixel) ----------
  if (t < 32) {
    const int m15 = t & 15, mtt = t >> 4;
    float mx = -3.0e38f;
    for (int i = 0; i < 49; ++i)
      mx = fmaxf(mx, lg2[0][t][i] + lg2[1][t][i]);
    float s = 0.f;
    for (int i = 0; i < 49; ++i)
      s += __expf(lg2[0][t][i] + lg2[1][t][i] - mx);
    const float inv = 1.f / s;
    #pragma unroll
    for (int dh = 0; dh < 7; ++dh)
      #pragma unroll
      for (int dw = 0; dw < 7; ++dw) {
        float l = lg2[0][t][dh * 7 + dw] + lg2[1][t][dh * 7 + dw];
        pb[mtt][dh][m15][m15 + 5 + dw] = f2bf(__expf(l - mx) * inv);
      }
  }
  __syncthreads();

  // ---------- phase 2: out[c][m'] = sum_n' v[c][n'] * P[m'][n'] ----------
  #pragma unroll
  for (int i = 0; i < 4; ++i) {
    const int ct = wv * 4 + i;               // c-tile (16 channels)
    #pragma unroll
    for (int m2 = 0; m2 < 2; ++m2) {
      const int wb2 = half * 32 + m2 * 16;
      const int wo = wb2 - 8 + q4 * 8;       // A k-octet start (w coord)
      const bool wok = (wo >= 0) && (wo <= 56);
      const u16* vbase = vo + (ct * 16 + l15) * 16384 + wo;  // A: m = l15 (channel)
      f32x4 acc = {0.f, 0.f, 0.f, 0.f};
      for (int dh = 0; dh < 7; ++dh) {
        const int rdh = h + dh - 3;
        if (rdh < 0 || rdh >= 64) continue;  // v row OOB -> zero contribution
        const int rp = (row + dh - 3) * 64;
        short8 af = wok ? *(const short8*)(vbase + rp) : zf;
        short8 bf_ = *(const short8*)(&pb[m2][dh][l15][q4 * 8]);
        acc = __builtin_amdgcn_mfma_f32_16x16x32_bf16(af, bf_, acc, 0, 0, 0);
      }
      // D: row m = channel q4*4+r, col n = pixel l15 -> native [b][c][h][w]
      #pragma unroll
      for (int r = 0; r < 4; ++r)
        out[(b * 256 + ct * 16 + q4 * 4 + r) * 4096 + h * 64 + wb2 + l15] = acc[r];
    }
  }
}

extern "C" void kernel_launch(void* const* d_in, const int* in_sizes, int n_in,
                              void* d_out, int out_size, void* d_ws, size_t ws_size,
                              hipStream_t stream)
{
  const float* x  = (const float*)d_in[0];
  const float* w1 = (const float*)d_in[1];
  const float* w2 = (const float*)d_in[2];
  const float* w3 = (const float*)d_in[3];
  float* out = (float*)d_out;

  char* ws = (char*)d_ws;
  u16* XTh = (u16*)ws;                     // 8 MB bf16 hi(x), pixel-major [pix][c]
  u16* XTl = (u16*)(ws + (8u  << 20));     // 8 MB bf16 lo(x)
  u16* yh_ = (u16*)(ws + (16u << 20));     // 8 MB bf16 hi(y = Mx), pixel-major
  u16* yl_ = (u16*)(ws + (24u << 20));     // 8 MB bf16 lo(y)
  u16* vo  = (u16*)(ws + (32u << 20));     // 8 MB bf16 v, c-major [c][pix]
  u16* W3h = (u16*)(ws + (40u << 20));     // 128 KB
  u16* Mh  = W3h + 65536;                  // 128 KB
  u16* Ml  = Mh + 65536;                   // 128 KB

  prep<<<1344, 256, 0, stream>>>(x, w1, w2, w3, XTh, XTl, W3h, Mh, Ml);
  yv_gemm<<<dim3(128, 2, 2), 256, 0, stream>>>(XTh, XTl, Mh, Ml, W3h, yh_, yl_, vo);
  attn<<<512, 256, 0, stream>>>(XTh, XTl, yh_, yl_, vo, out);
}